// Round 8
// baseline (2339.612 us; speedup 1.0000x reference)
//
#include <hip/hip_runtime.h>

// GCN pipeline (R19 = bucket-direct LDS-accumulate aggregation; sortcsr/csr
// deleted. R18 established the gather is transaction-rate-bound (~0.13 random
// line-transactions/cy/CU, invariant to L2 residency/occupancy/ILP), so this
// round keeps the gather at its wall and deletes work around it):
//   k_hist:   per-bucket(128 dst) edge counts (BSHIFT=7, 1024-max buckets)
//   k_binA:   tile-wise LDS counting sort by bucket -> binned (src|dstlo<<17);
//             inline 1024-bucket scan (4/thread); block 0 dumps bko[] offsets
//   k_deg:    per-bucket LDS hist of binned dstlo -> dinv
//   k_gemm:   hsb = pack_bf16((X @ W1) * dinv[row])  (R16 verbatim)
//   k_agg1L:  block/bucket: gather hsb rows (8 lanes x uint4), ds_add_f32 into
//             LDS acc[feat][129-stride node] (transposed: bank-conflict-free);
//             self as 128 virtual edges; dump raw fp32 sums -> agg[node][64]
//   k_fin64:  relu(agg*di+b1) @ W2, pack -> hsb2 (R18 verbatim, verified)
//   k_agg2L:  same as agg1L for layer 2 (hsb2 rows, 32 feats) -> agg2
//   k_fin32:  relu(agg2*di+b2) @ Wc + bc, log_softmax -> out (agg32f tail)

#define BSHIFT 7
#define BMASK 127
#define NBUCK_MAX 1024
#define TILE 4096
#define EPT 16             // TILE / 256
#define NPW 4              // nodes per wave in fin kernels

__device__ __forceinline__ unsigned pack_bf16(float lo, float hi) {
    unsigned ul = __float_as_uint(lo);
    ul = (ul + 0x7FFFu + ((ul >> 16) & 1u)) >> 16;
    unsigned uh = __float_as_uint(hi);
    uh = ((uh + 0x7FFFu + ((uh >> 16) & 1u)) >> 16) << 16;
    return ul | uh;
}

__global__ void k_hist(const int* __restrict__ dst, int* __restrict__ bcnt, int E) {
    __shared__ int h[NBUCK_MAX];
    for (int i = threadIdx.x; i < NBUCK_MAX; i += blockDim.x) h[i] = 0;
    __syncthreads();
    for (int e = blockIdx.x * blockDim.x + threadIdx.x; e < E; e += gridDim.x * blockDim.x)
        atomicAdd(&h[dst[e] >> BSHIFT], 1);
    __syncthreads();
    for (int i = threadIdx.x; i < NBUCK_MAX; i += blockDim.x)
        if (h[i]) atomicAdd(&bcnt[i], h[i]);
}

// Tile-wise LDS counting sort by bucket; dump contiguous per-bucket runs.
// Inline exclusive scans are 4 entries/thread (1024 buckets, 256 threads).
__global__ __launch_bounds__(256) void k_binA(const int* __restrict__ src,
                                              const int* __restrict__ dst,
                                              const int* __restrict__ bcnt,
                                              int* __restrict__ gcur0,
                                              int* __restrict__ binned,
                                              int* __restrict__ bko, int E) {
    __shared__ int hist[NBUCK_MAX];
    __shared__ int lbase[NBUCK_MAX];
    __shared__ int gbase[NBUCK_MAX];
    __shared__ int gdelta[NBUCK_MAX];
    __shared__ int cnt2[NBUCK_MAX];
    __shared__ int scan1[256];
    __shared__ int stage[TILE];
    __shared__ unsigned short sbucket[TILE];

    int t = threadIdx.x;
    for (int i = t; i < NBUCK_MAX; i += 256) { hist[i] = 0; cnt2[i] = 0; }
    // global bucket-base scan of bcnt (4/thread)
    int c0 = bcnt[4 * t], c1 = bcnt[4 * t + 1], c2 = bcnt[4 * t + 2], c3 = bcnt[4 * t + 3];
    int ts = c0 + c1 + c2 + c3;
    scan1[t] = ts;
    __syncthreads();
    for (int o = 1; o < 256; o <<= 1) {
        int u = (t >= o) ? scan1[t - o] : 0;
        __syncthreads();
        scan1[t] += u;
        __syncthreads();
    }
    int ex = scan1[t] - ts;
    gbase[4 * t]     = ex;
    gbase[4 * t + 1] = ex + c0;
    gbase[4 * t + 2] = ex + c0 + c1;
    gbase[4 * t + 3] = ex + c0 + c1 + c2;
    __syncthreads();
    if (blockIdx.x == 0) {
        for (int i = t; i < NBUCK_MAX; i += 256) bko[i] = gbase[i];
        if (t == 0) bko[NBUCK_MAX] = E;
    }

    int tileStart = blockIdx.x * TILE;
    int cntTile = min(TILE, E - tileStart);

    int vals[EPT];
    int bks[EPT];
#pragma unroll
    for (int i = 0; i < EPT; i++) {
        int e = tileStart + t + i * 256;
        if (e < E) {
            int s = src[e], d = dst[e];
            vals[i] = s | ((d & BMASK) << 17);
            bks[i] = d >> BSHIFT;
            atomicAdd(&hist[bks[i]], 1);
        } else bks[i] = -1;
    }
    __syncthreads();

    // tile-local base scan of hist (4/thread, reuses scan1 after barrier)
    int a0 = hist[4 * t], a1 = hist[4 * t + 1], a2 = hist[4 * t + 2], a3 = hist[4 * t + 3];
    int ls = a0 + a1 + a2 + a3;
    scan1[t] = ls;
    __syncthreads();
    for (int o = 1; o < 256; o <<= 1) {
        int u = (t >= o) ? scan1[t - o] : 0;
        __syncthreads();
        scan1[t] += u;
        __syncthreads();
    }
    int lx = scan1[t] - ls;
    lbase[4 * t]     = lx;
    lbase[4 * t + 1] = lx + a0;
    lbase[4 * t + 2] = lx + a0 + a1;
    lbase[4 * t + 3] = lx + a0 + a1 + a2;
    __syncthreads();

    for (int b = t; b < NBUCK_MAX; b += 256) {
        int c = hist[b];
        int g = c ? (gbase[b] + atomicAdd(&gcur0[b], c)) : 0;
        gdelta[b] = g - lbase[b];
    }
#pragma unroll
    for (int i = 0; i < EPT; i++) {
        if (bks[i] >= 0) {
            int rr = atomicAdd(&cnt2[bks[i]], 1);
            int slot = lbase[bks[i]] + rr;
            stage[slot] = vals[i];
            sbucket[slot] = (unsigned short)bks[i];
        }
    }
    __syncthreads();
    for (int i = t; i < cntTile; i += 256) {
        int b = sbucket[i];
        binned[gdelta[b] + i] = stage[i];
    }
}

// Per-bucket degree -> dinv.
__global__ __launch_bounds__(256) void k_deg(const int* __restrict__ bko,
                                             const int* __restrict__ binned,
                                             float* __restrict__ dinv, int n) {
    __shared__ int cnt[128];
    int b = blockIdx.x, t = threadIdx.x;
    if (t < 128) cnt[t] = 0;
    __syncthreads();
    int beg = bko[b], end = bko[b + 1];
    for (int i = beg + t; i < end; i += 256)
        atomicAdd(&cnt[(binned[i] >> 17) & BMASK], 1);
    __syncthreads();
    int g = (b << BSHIFT) + t;
    if (t < 128 && g < n) dinv[g] = rsqrtf((float)cnt[t] + 1.0f);
}

// hsb = pack_bf16((X @ W) * dinv[row]); R16 verbatim.
template<int K, int M, int R>
__global__ __launch_bounds__(256) void k_gemm(const float* __restrict__ X,
                                              const float* __restrict__ W,
                                              const float* __restrict__ dinv,
                                              unsigned* __restrict__ hsb, int n) {
    constexpr int MW = M / 4;       // cols per wave
    __shared__ float Ws[K * M];
    for (int i = threadIdx.x; i < K * M; i += 256) Ws[i] = W[i];
    __syncthreads();
    int w = threadIdx.x >> 6, lane = threadIdx.x & 63;
    int wo = w * MW;
    int r0 = blockIdx.x * (64 * R) + lane;
    float acc[R][MW];
#pragma unroll
    for (int i = 0; i < R; i++)
#pragma unroll
        for (int j = 0; j < MW; j++) acc[i][j] = 0.f;

    for (int k = 0; k < K; k += 4) {
        float4 xv[R];
#pragma unroll
        for (int i = 0; i < R; i++) {
            int rr = r0 + 64 * i;
            xv[i] = (rr < n) ? *(const float4*)(X + (size_t)rr * K + k)
                             : make_float4(0.f, 0.f, 0.f, 0.f);
        }
#pragma unroll
        for (int kk = 0; kk < 4; kk++) {
#pragma unroll
            for (int j = 0; j < MW; j += 4) {
                float4 wv = *(const float4*)&Ws[(k + kk) * M + wo + j];
#pragma unroll
                for (int i = 0; i < R; i++) {
                    float xs = (kk == 0) ? xv[i].x : (kk == 1) ? xv[i].y
                             : (kk == 2) ? xv[i].z : xv[i].w;
                    acc[i][j + 0] += xs * wv.x;
                    acc[i][j + 1] += xs * wv.y;
                    acc[i][j + 2] += xs * wv.z;
                    acc[i][j + 3] += xs * wv.w;
                }
            }
        }
    }
#pragma unroll
    for (int i = 0; i < R; i++) {
        int rr = r0 + 64 * i;
        if (rr < n) {
            float di = dinv[rr];
            unsigned p[MW / 2];
#pragma unroll
            for (int jj = 0; jj < MW / 2; jj++)
                p[jj] = pack_bf16(acc[i][2 * jj] * di, acc[i][2 * jj + 1] * di);
            unsigned* hr = hsb + (size_t)rr * (M / 2) + wo / 2;
#pragma unroll
            for (int jj = 0; jj < MW / 2; jj += 4)
                *(uint4*)(hr + jj) = make_uint4(p[jj], p[jj + 1], p[jj + 2], p[jj + 3]);
        }
    }
}

// Layer-1 bucket aggregation: block per bucket. Lane (e=lane>>3 edge-slot,
// f=lane&7 word). Gather hsb[src] row (128B), ds_add unpacked bf16 into
// acc[feat][node] (stride 129: bank = (feat + node) % 32, conflict ~2-way).
// Self-loop = 128 virtual edges (ii<128). Dump raw fp32 sums -> agg[node][64].
__global__ __launch_bounds__(256) void k_agg1L(const int* __restrict__ bko,
                                               const int* __restrict__ binned,
                                               const uint4* __restrict__ hsb,
                                               float* __restrict__ agg, int n) {
    __shared__ float acc[64 * 129];
    int t = threadIdx.x, b = blockIdx.x;
    int node0 = b << BSHIFT;
    int beg = bko[b], end = bko[b + 1];
    int cnt = 128 + (end - beg);
    for (int i = t; i < 64 * 129; i += 256) acc[i] = 0.f;
    __syncthreads();
    int wv = t >> 6, lane = t & 63, e = lane >> 3, f = lane & 7;
    for (int base = wv * 8; base < cnt; base += 32) {
        int ii = base + e;
        int srcn = 0, dl = 0;
        bool ok = false;
        if (ii < 128) { srcn = node0 + ii; dl = ii; ok = srcn < n; }
        else if (ii < cnt) {
            int v = binned[beg + ii - 128];
            srcn = v & 0x1FFFF; dl = (v >> 17) & BMASK; ok = true;
        }
        if (ok) {
            uint4 w = hsb[(size_t)srcn * 8 + f];
            atomicAdd(&acc[(8 * f + 0) * 129 + dl], __uint_as_float(w.x << 16));
            atomicAdd(&acc[(8 * f + 1) * 129 + dl], __uint_as_float(w.x & 0xFFFF0000u));
            atomicAdd(&acc[(8 * f + 2) * 129 + dl], __uint_as_float(w.y << 16));
            atomicAdd(&acc[(8 * f + 3) * 129 + dl], __uint_as_float(w.y & 0xFFFF0000u));
            atomicAdd(&acc[(8 * f + 4) * 129 + dl], __uint_as_float(w.z << 16));
            atomicAdd(&acc[(8 * f + 5) * 129 + dl], __uint_as_float(w.z & 0xFFFF0000u));
            atomicAdd(&acc[(8 * f + 6) * 129 + dl], __uint_as_float(w.w << 16));
            atomicAdd(&acc[(8 * f + 7) * 129 + dl], __uint_as_float(w.w & 0xFFFF0000u));
        }
    }
    __syncthreads();
    for (int i = t; i < 128 * 64; i += 256) {
        int nl = i >> 6, ft = i & 63;
        int node = node0 + nl;
        if (node < n) agg[(size_t)node * 64 + ft] = acc[ft * 129 + nl];
    }
}

// Streaming finish: v = relu(agg*di + b1); in-register 64x32 gemm; pack -> hsb2.
// R18 verbatim (verified). Lane (q=lane>>3, r=lane&7).
__global__ __launch_bounds__(256) void k_fin64(
        const float* __restrict__ agg, const float* __restrict__ dinv,
        const float* __restrict__ b1, const float* __restrict__ W2,
        unsigned* __restrict__ hsb2, int n) {
    int wid = (blockIdx.x * blockDim.x + threadIdx.x) >> 6;
    int lane = threadIdx.x & 63;
    int q = lane >> 3, r = lane & 7;
    int d0 = wid * NPW;
    if (d0 >= n) return;
    float w2r[8][4];
    float b1r[8];
#pragma unroll
    for (int i = 0; i < 8; i++) {
        b1r[i] = b1[8 * r + i];
#pragma unroll
        for (int jj = 0; jj < 4; jj++)
            w2r[i][jj] = W2[(8 * r + i) * 32 + 4 * q + jj];
    }
    int dend = min(d0 + NPW, n);
    for (int d = d0; d < dend; d++) {
        float4 x0 = *(const float4*)(agg + (size_t)d * 64 + 8 * r);
        float4 x1 = *(const float4*)(agg + (size_t)d * 64 + 8 * r + 4);
        float di = dinv[d];
        float v[8];
        v[0] = fmaxf(x0.x * di + b1r[0], 0.f);
        v[1] = fmaxf(x0.y * di + b1r[1], 0.f);
        v[2] = fmaxf(x0.z * di + b1r[2], 0.f);
        v[3] = fmaxf(x0.w * di + b1r[3], 0.f);
        v[4] = fmaxf(x1.x * di + b1r[4], 0.f);
        v[5] = fmaxf(x1.y * di + b1r[5], 0.f);
        v[6] = fmaxf(x1.z * di + b1r[6], 0.f);
        v[7] = fmaxf(x1.w * di + b1r[7], 0.f);
        float h[4] = {0.f, 0.f, 0.f, 0.f};
#pragma unroll
        for (int i = 0; i < 8; i++)
#pragma unroll
            for (int jj = 0; jj < 4; jj++) h[jj] += v[i] * w2r[i][jj];
#pragma unroll
        for (int jj = 0; jj < 4; jj++) {
            h[jj] += __shfl_xor(h[jj], 1, 64);
            h[jj] += __shfl_xor(h[jj], 2, 64);
            h[jj] += __shfl_xor(h[jj], 4, 64);
        }
        if (r == 0) {
            unsigned p0 = pack_bf16(h[0] * di, h[1] * di);
            unsigned p1 = pack_bf16(h[2] * di, h[3] * di);
            *(uint2*)(hsb2 + (size_t)d * 16 + 2 * q) = make_uint2(p0, p1);
        }
    }
}

// Layer-2 bucket aggregation: lane (e=lane>>2 in 0..15, f=lane&3).
// Gather hsb2[src] row (64B); ds_add into acc[feat][node] (32x129).
__global__ __launch_bounds__(256) void k_agg2L(const int* __restrict__ bko,
                                               const int* __restrict__ binned,
                                               const uint4* __restrict__ hsb2,
                                               float* __restrict__ agg2, int n) {
    __shared__ float acc[32 * 129];
    int t = threadIdx.x, b = blockIdx.x;
    int node0 = b << BSHIFT;
    int beg = bko[b], end = bko[b + 1];
    int cnt = 128 + (end - beg);
    for (int i = t; i < 32 * 129; i += 256) acc[i] = 0.f;
    __syncthreads();
    int wv = t >> 6, lane = t & 63, e = lane >> 2, f = lane & 3;
    for (int base = wv * 16; base < cnt; base += 64) {
        int ii = base + e;
        int srcn = 0, dl = 0;
        bool ok = false;
        if (ii < 128) { srcn = node0 + ii; dl = ii; ok = srcn < n; }
        else if (ii < cnt) {
            int v = binned[beg + ii - 128];
            srcn = v & 0x1FFFF; dl = (v >> 17) & BMASK; ok = true;
        }
        if (ok) {
            uint4 w = hsb2[(size_t)srcn * 4 + f];
            atomicAdd(&acc[(8 * f + 0) * 129 + dl], __uint_as_float(w.x << 16));
            atomicAdd(&acc[(8 * f + 1) * 129 + dl], __uint_as_float(w.x & 0xFFFF0000u));
            atomicAdd(&acc[(8 * f + 2) * 129 + dl], __uint_as_float(w.y << 16));
            atomicAdd(&acc[(8 * f + 3) * 129 + dl], __uint_as_float(w.y & 0xFFFF0000u));
            atomicAdd(&acc[(8 * f + 4) * 129 + dl], __uint_as_float(w.z << 16));
            atomicAdd(&acc[(8 * f + 5) * 129 + dl], __uint_as_float(w.z & 0xFFFF0000u));
            atomicAdd(&acc[(8 * f + 6) * 129 + dl], __uint_as_float(w.w << 16));
            atomicAdd(&acc[(8 * f + 7) * 129 + dl], __uint_as_float(w.w & 0xFFFF0000u));
        }
    }
    __syncthreads();
    for (int i = t; i < 128 * 32; i += 256) {
        int nl = i >> 5, ft = i & 31;
        int node = node0 + nl;
        if (node < n) agg2[(size_t)node * 32 + ft] = acc[ft * 129 + nl];
    }
}

// Classifier finish: v = relu(agg2*di + b2); logits = v @ Wc + bc; log_softmax.
// Tail logic identical to the verified agg32f epilogue (self already in agg2).
__global__ __launch_bounds__(256) void k_fin32(
        const float* __restrict__ agg2, const float* __restrict__ dinv,
        const float* __restrict__ b2, const float* __restrict__ Wc,
        const float* __restrict__ bc, float* __restrict__ out, int n) {
    int wid = (blockIdx.x * blockDim.x + threadIdx.x) >> 6;
    int lane = threadIdx.x & 63;
    int q = lane >> 2, r = lane & 3;
    int d0 = wid * NPW;
    if (d0 >= n) return;
    float wcr[8];
    float b2r[8];
    float bcr = (q < 10) ? bc[q] : 0.f;
#pragma unroll
    for (int i = 0; i < 8; i++) {
        b2r[i] = b2[8 * r + i];
        wcr[i] = (q < 10) ? Wc[(8 * r + i) * 10 + q] : 0.f;
    }
    int dend = min(d0 + NPW, n);
    for (int d = d0; d < dend; d++) {
        float4 x0 = *(const float4*)(agg2 + (size_t)d * 32 + 8 * r);
        float4 x1 = *(const float4*)(agg2 + (size_t)d * 32 + 8 * r + 4);
        float di = dinv[d];
        float a[8] = {x0.x, x0.y, x0.z, x0.w, x1.x, x1.y, x1.z, x1.w};
        float part = 0.f;
#pragma unroll
        for (int i = 0; i < 8; i++) {
            float v = fmaxf(a[i] * di + b2r[i], 0.f);
            part += v * wcr[i];
        }
        part += __shfl_xor(part, 1, 64);
        part += __shfl_xor(part, 2, 64);
        float mylogit = part + bcr;
        float m = -1e30f;
        float l[10];
#pragma unroll
        for (int c = 0; c < 10; c++) {
            l[c] = __shfl(mylogit, 4 * c, 64);
            m = fmaxf(m, l[c]);
        }
        float ssum = 0.f;
#pragma unroll
        for (int c = 0; c < 10; c++) ssum += __expf(l[c] - m);
        float lse = m + __logf(ssum);
        if (r == 0 && q < 10) out[(size_t)d * 10 + q] = mylogit - lse;
    }
}

extern "C" void kernel_launch(void* const* d_in, const int* in_sizes, int n_in,
                              void* d_out, int out_size, void* d_ws, size_t ws_size,
                              hipStream_t stream) {
    const float* x  = (const float*)d_in[0];
    const int*   ei = (const int*)d_in[1];
    const float* W1 = (const float*)d_in[2];
    const float* b1 = (const float*)d_in[3];
    const float* W2 = (const float*)d_in[4];
    const float* b2 = (const float*)d_in[5];
    const float* Wc = (const float*)d_in[6];
    const float* bc = (const float*)d_in[7];
    float* out = (float*)d_out;

    const int N = in_sizes[0] / 128;
    const int E = in_sizes[1] / 2;
    const int* src = ei;
    const int* dst = ei + E;

    const int NBUCK = (N + BMASK) >> BSHIFT;   // <= 1024
    const int NTILE = (E + TILE - 1) / TILE;
    const int NW = (N + NPW - 1) / NPW;        // waves for fin kernels

    char* ws = (char*)d_ws;
    size_t off = 0;
    auto alloc = [&](size_t elems) {
        void* p = ws + off;
        off += ((elems * 4 + 1023) & ~(size_t)1023);
        return p;
    };
    float*    dinv   = (float*)alloc(N);
    int*      bcnt   = (int*)alloc(NBUCK_MAX);   // adjacent to gcur0: one memset
    int*      gcur0  = (int*)alloc(NBUCK_MAX);
    int*      bko    = (int*)alloc(NBUCK_MAX + 1);
    int*      binned = (int*)alloc(E);
    unsigned* hsb    = (unsigned*)alloc((size_t)N * 32);  // layer1 bf16 rows (128 B)
    unsigned* hsb2   = (unsigned*)alloc((size_t)N * 16);  // layer2 bf16 rows (64 B)
    float*    agg    = (float*)alloc((size_t)N * 64);     // layer1 fp32 sums
    float*    agg2   = (float*)alloc((size_t)N * 32);     // layer2 fp32 sums

    hipMemsetAsync(bcnt, 0, sizeof(int) * NBUCK_MAX * 2, stream);  // bcnt + gcur0

    // Build: bucket counts -> grouped edges (+bko offsets) -> degrees
    k_hist<<<512, 256, 0, stream>>>(dst, bcnt, E);
    k_binA<<<NTILE, 256, 0, stream>>>(src, dst, bcnt, gcur0, binned, bko, E);
    k_deg<<<NBUCK, 256, 0, stream>>>(bko, binned, dinv, N);

    // Layer 1: 128 -> 64
    k_gemm<128, 64, 2><<<(N + 127) / 128, 256, 0, stream>>>(x, W1, dinv, hsb, N);
    k_agg1L<<<NBUCK, 256, 0, stream>>>(bko, binned, (const uint4*)hsb, agg, N);
    k_fin64<<<(NW * 64 + 255) / 256, 256, 0, stream>>>(agg, dinv, b1, W2, hsb2, N);

    // Layer 2: 64 -> 32 -> classifier
    k_agg2L<<<NBUCK, 256, 0, stream>>>(bko, binned, (const uint4*)hsb2, agg2, N);
    k_fin32<<<(NW * 64 + 255) / 256, 256, 0, stream>>>(agg2, dinv, b2, Wc, bc, out, N);
}

// Round 10
// 359.113 us; speedup vs baseline: 6.5150x; 6.5150x over previous
//
#include <hip/hip_runtime.h>

// GCN pipeline (R21 = R16 restored verbatim — verified 360.0us).
// R20's k_hist-deletion variant core-dumped; its ~10us target does not
// justify risk against this verified state. Session findings:
//  - Random row-gather pinned at ~0.13 segments/cy/CU (per-CU miss
//    concurrency wall): invariant to occupancy (38% vs 78%, R16/R18),
//    per-wave ILP (R17 null), schedule (R12-R14), L2 residency (R18:
//    FETCH 155->52MB yet slower), LDS accumulation (R19 disaster).
//    agg64f+agg32f are at this floor (~135-140us combined).
//  - Random fine-grain global scatter = 15x write amplification (R15);
//    LDS-stage-then-coalesced-dump is the law for the CSR build.
//   k_hist:    per-bucket(256 dst nodes) edge counts, LDS hist -> bcnt
//   k_binA:    tile-wise LDS counting sort by bucket -> binned (src|dstlo<<17);
//              inlines the 512-bucket scan of bcnt
//   k_sortcsr: per-bucket dstlo hist+scan -> rowptr, dinv; LDS-staged csr dump
//   k_gemm<K,M,R>: hsb = pack_bf16((X @ W) * dinv[row])
//   k_agg64f:  wave-per-node bf16 gather + relu + in-register 64x32 gemm
//   k_agg32f:  layer-2 aggregate + relu + 32x10 classifier + log_softmax

#define BSHIFT 8
#define BMASK 255
#define NBUCK_MAX 512
#define TILE 4096
#define EPT 16             // TILE / 256
#define NPW 4              // nodes per wave in fused agg kernels
#define SCAP 12288         // sortcsr LDS stage capacity (mean bucket 8192, +45 sigma)

__device__ __forceinline__ unsigned pack_bf16(float lo, float hi) {
    unsigned ul = __float_as_uint(lo);
    ul = (ul + 0x7FFFu + ((ul >> 16) & 1u)) >> 16;
    unsigned uh = __float_as_uint(hi);
    uh = ((uh + 0x7FFFu + ((uh >> 16) & 1u)) >> 16) << 16;
    return ul | uh;
}

__global__ void k_hist(const int* __restrict__ dst, int* __restrict__ bcnt, int E) {
    __shared__ int h[NBUCK_MAX];
    for (int i = threadIdx.x; i < NBUCK_MAX; i += blockDim.x) h[i] = 0;
    __syncthreads();
    for (int e = blockIdx.x * blockDim.x + threadIdx.x; e < E; e += gridDim.x * blockDim.x)
        atomicAdd(&h[dst[e] >> BSHIFT], 1);
    __syncthreads();
    for (int i = threadIdx.x; i < NBUCK_MAX; i += blockDim.x)
        if (h[i]) atomicAdd(&bcnt[i], h[i]);
}

// Tile-wise LDS counting sort by bucket; dump contiguous per-bucket runs.
// Inline 512-entry exclusive scan of bcnt -> gbase (no k_scanb dispatch).
__global__ __launch_bounds__(256) void k_binA(const int* __restrict__ src,
                                              const int* __restrict__ dst,
                                              const int* __restrict__ bcnt,
                                              int* __restrict__ gcur0,
                                              int* __restrict__ binned, int E) {
    __shared__ int hist[NBUCK_MAX];
    __shared__ int lbase[NBUCK_MAX];
    __shared__ int gbase[NBUCK_MAX];
    __shared__ int gdelta[NBUCK_MAX];
    __shared__ int cnt2[NBUCK_MAX];
    __shared__ int scanb[256];
    __shared__ int scanc[256];
    __shared__ int stage[TILE];
    __shared__ unsigned short sbucket[TILE];

    int t = threadIdx.x;
    for (int i = t; i < NBUCK_MAX; i += 256) { hist[i] = 0; cnt2[i] = 0; }
    // inline exclusive scan of bcnt (2 entries/thread)
    int c0 = bcnt[2 * t], c1 = bcnt[2 * t + 1];
    int cs = c0 + c1;
    scanc[t] = cs;
    __syncthreads();
    for (int o = 1; o < 256; o <<= 1) {
        int u = (t >= o) ? scanc[t - o] : 0;
        __syncthreads();
        scanc[t] += u;
        __syncthreads();
    }
    int ex2 = scanc[t] - cs;
    gbase[2 * t] = ex2;
    gbase[2 * t + 1] = ex2 + c0;
    __syncthreads();

    int tileStart = blockIdx.x * TILE;
    int cntTile = min(TILE, E - tileStart);

    int vals[EPT];
    int bks[EPT];
#pragma unroll
    for (int i = 0; i < EPT; i++) {
        int e = tileStart + t + i * 256;
        if (e < E) {
            int s = src[e], d = dst[e];
            vals[i] = s | ((d & BMASK) << 17);
            bks[i] = d >> BSHIFT;
            atomicAdd(&hist[bks[i]], 1);
        } else bks[i] = -1;
    }
    __syncthreads();

    int a0 = hist[2 * t], a1 = hist[2 * t + 1];
    int ts = a0 + a1;
    scanb[t] = ts;
    __syncthreads();
    for (int o = 1; o < 256; o <<= 1) {
        int u = (t >= o) ? scanb[t - o] : 0;
        __syncthreads();
        scanb[t] += u;
        __syncthreads();
    }
    int ex = scanb[t] - ts;
    lbase[2 * t] = ex;
    lbase[2 * t + 1] = ex + a0;
    __syncthreads();

    for (int b = t; b < NBUCK_MAX; b += 256) {
        int c = hist[b];
        int g = c ? (gbase[b] + atomicAdd(&gcur0[b], c)) : 0;
        gdelta[b] = g - lbase[b];
    }
#pragma unroll
    for (int i = 0; i < EPT; i++) {
        if (bks[i] >= 0) {
            int rr = atomicAdd(&cnt2[bks[i]], 1);
            int slot = lbase[bks[i]] + rr;
            stage[slot] = vals[i];
            sbucket[slot] = (unsigned short)bks[i];
        }
    }
    __syncthreads();
    for (int i = t; i < cntTile; i += 256) {
        int b = sbucket[i];
        binned[gdelta[b] + i] = stage[i];
    }
}

// Per-bucket: inline bcnt scan -> [beg,end); dstlo hist+scan -> rowptr, dinv;
// placement into LDS stage; coalesced dump -> csr.
__global__ __launch_bounds__(256) void k_sortcsr(const int* __restrict__ bcnt,
                                                 const int* __restrict__ binned,
                                                 int* __restrict__ rowptr,
                                                 float* __restrict__ dinv,
                                                 int* __restrict__ csr, int n, int E) {
    __shared__ int cnt[256];
    __shared__ int sc[256];
    __shared__ int rpl[256];
    __shared__ int lcur[256];
    __shared__ int gbase[NBUCK_MAX];
    __shared__ int scanc[256];
    __shared__ int stage2[SCAP];
    int b = blockIdx.x, t = threadIdx.x;
    cnt[t] = 0; lcur[t] = 0;
    int c0 = bcnt[2 * t], c1 = bcnt[2 * t + 1];
    int cs = c0 + c1;
    scanc[t] = cs;
    __syncthreads();
    for (int o = 1; o < 256; o <<= 1) {
        int u = (t >= o) ? scanc[t - o] : 0;
        __syncthreads();
        scanc[t] += u;
        __syncthreads();
    }
    int ex2 = scanc[t] - cs;
    gbase[2 * t] = ex2;
    gbase[2 * t + 1] = ex2 + c0;
    __syncthreads();

    int beg = gbase[b];
    int end = (b + 1 < NBUCK_MAX) ? gbase[b + 1] : E;
    for (int i = beg + t; i < end; i += 256)
        atomicAdd(&cnt[(binned[i] >> 17) & BMASK], 1);
    __syncthreads();
    int v = cnt[t];
    sc[t] = v;
    __syncthreads();
    for (int o = 1; o < 256; o <<= 1) {
        int u = (t >= o) ? sc[t - o] : 0;
        __syncthreads();
        sc[t] += u;
        __syncthreads();
    }
    int rp = beg + sc[t] - v;
    rpl[t] = rp;
    int g = (b << BSHIFT) + t;
    if (g < n) {
        rowptr[g] = rp;
        dinv[g] = rsqrtf((float)v + 1.0f);
        if (g == n - 1) rowptr[n] = E;
    }
    __syncthreads();
    for (int i = beg + t; i < end; i += 256) {
        int vv = binned[i];
        int ln = (vv >> 17) & BMASK;
        int k = atomicAdd(&lcur[ln], 1);
        int idx = rpl[ln] + k - beg;
        if (idx < SCAP) stage2[idx] = vv & 0x1FFFF;
        else            csr[beg + idx] = vv & 0x1FFFF;   // ~never
    }
    __syncthreads();
    int cc = end - beg;
    for (int i = t; i < cc; i += 256)
        if (i < SCAP) csr[beg + i] = stage2[i];
}

// hsb = pack_bf16((X @ W) * dinv[row]); block = 64*R rows (R rows/thread);
// wave w owns cols [w*M/4, (w+1)*M/4): Ws float4 reads are wave-uniform
// (LDS broadcast, conflict-free).
template<int K, int M, int R>
__global__ __launch_bounds__(256) void k_gemm(const float* __restrict__ X,
                                              const float* __restrict__ W,
                                              const float* __restrict__ dinv,
                                              unsigned* __restrict__ hsb, int n) {
    constexpr int MW = M / 4;       // cols per wave
    __shared__ float Ws[K * M];
    for (int i = threadIdx.x; i < K * M; i += 256) Ws[i] = W[i];
    __syncthreads();
    int w = threadIdx.x >> 6, lane = threadIdx.x & 63;
    int wo = w * MW;
    int r0 = blockIdx.x * (64 * R) + lane;
    float acc[R][MW];
#pragma unroll
    for (int i = 0; i < R; i++)
#pragma unroll
        for (int j = 0; j < MW; j++) acc[i][j] = 0.f;

    for (int k = 0; k < K; k += 4) {
        float4 xv[R];
#pragma unroll
        for (int i = 0; i < R; i++) {
            int rr = r0 + 64 * i;
            xv[i] = (rr < n) ? *(const float4*)(X + (size_t)rr * K + k)
                             : make_float4(0.f, 0.f, 0.f, 0.f);
        }
#pragma unroll
        for (int kk = 0; kk < 4; kk++) {
#pragma unroll
            for (int j = 0; j < MW; j += 4) {
                float4 wv = *(const float4*)&Ws[(k + kk) * M + wo + j];
#pragma unroll
                for (int i = 0; i < R; i++) {
                    float xs = (kk == 0) ? xv[i].x : (kk == 1) ? xv[i].y
                             : (kk == 2) ? xv[i].z : xv[i].w;
                    acc[i][j + 0] += xs * wv.x;
                    acc[i][j + 1] += xs * wv.y;
                    acc[i][j + 2] += xs * wv.z;
                    acc[i][j + 3] += xs * wv.w;
                }
            }
        }
    }
#pragma unroll
    for (int i = 0; i < R; i++) {
        int rr = r0 + 64 * i;
        if (rr < n) {
            float di = dinv[rr];
            unsigned p[MW / 2];
#pragma unroll
            for (int jj = 0; jj < MW / 2; jj++)
                p[jj] = pack_bf16(acc[i][2 * jj] * di, acc[i][2 * jj + 1] * di);
            unsigned* hr = hsb + (size_t)rr * (M / 2) + wo / 2;
#pragma unroll
            for (int jj = 0; jj < MW / 2; jj += 4)
                *(uint4*)(hr + jj) = make_uint4(p[jj], p[jj + 1], p[jj + 2], p[jj + 3]);
        }
    }
}

#define ACC8(V) \
    acc[0] += __uint_as_float((V).x << 16);  acc[1] += __uint_as_float((V).x & 0xFFFF0000u); \
    acc[2] += __uint_as_float((V).y << 16);  acc[3] += __uint_as_float((V).y & 0xFFFF0000u); \
    acc[4] += __uint_as_float((V).z << 16);  acc[5] += __uint_as_float((V).z & 0xFFFF0000u); \
    acc[6] += __uint_as_float((V).w << 16);  acc[7] += __uint_as_float((V).w & 0xFFFF0000u);

// Fused layer-1 aggregate + relu + 64x32 gemm + bf16 pack -> hsb2.
// Wave per node-group (NPW nodes). Lane (q=lane>>3, r=lane&7).
// Gather: 8 lanes/row (uint4 = 8 bf16 feats), edge slot q.
__global__ __launch_bounds__(256) void k_agg64f(
        const int* __restrict__ rowptr, const int* __restrict__ csr,
        const uint4* __restrict__ hsb, const float* __restrict__ dinv,
        const float* __restrict__ b1, const float* __restrict__ W2,
        unsigned* __restrict__ hsb2, int n) {
    int wid = (blockIdx.x * blockDim.x + threadIdx.x) >> 6;
    int lane = threadIdx.x & 63;
    int q = lane >> 3, r = lane & 7;
    int d0 = wid * NPW;
    if (d0 >= n) return;
    float w2r[8][4];
    float b1r[8];
#pragma unroll
    for (int i = 0; i < 8; i++) {
        b1r[i] = b1[8 * r + i];
#pragma unroll
        for (int jj = 0; jj < 4; jj++)
            w2r[i][jj] = W2[(8 * r + i) * 32 + 4 * q + jj];
    }
    int dend = min(d0 + NPW, n);
    int rp = rowptr[min(d0 + min(lane, NPW), n)];
    int beg = __shfl(rp, 0, 64);
    int end = __shfl(rp, 1, 64);
    int cc = min(end - beg, 64);
    int idxv = (lane < cc) ? csr[beg + lane] : 0;
    for (int d = d0; d < dend; d++) {
        int kk = d - d0;
        int nbeg = __shfl(rp, min(kk + 1, NPW), 64);
        int nend = __shfl(rp, min(kk + 2, NPW), 64);
        int ncc = min(nend - nbeg, 64);
        int nidxv = 0;
        if (d + 1 < dend) nidxv = (lane < ncc) ? csr[nbeg + lane] : 0;
        uint4 wsf = hsb[(size_t)d * 8 + r];   // self row: issue early
        float di = dinv[d];
        float acc[8];
#pragma unroll
        for (int i = 0; i < 8; i++) acc[i] = 0.f;
        int j = 0;
        for (; j + 16 <= cc; j += 16) {
            int sA = __shfl(idxv, j + q, 64);
            int sB = __shfl(idxv, j + 8 + q, 64);
            uint4 wA = hsb[(size_t)sA * 8 + r];
            uint4 wB = hsb[(size_t)sB * 8 + r];
            ACC8(wA)
            ACC8(wB)
        }
        {   // tail: shfl hoisted above the divergent guard (all lanes active)
            int tA = j + q, tB = j + 8 + q;
            int sA = __shfl(idxv, tA & 63, 64);
            int sB = __shfl(idxv, tB & 63, 64);
            if (tA < cc) { uint4 wv = hsb[(size_t)sA * 8 + r]; ACC8(wv) }
            if (tB < cc) { uint4 wv = hsb[(size_t)sB * 8 + r]; ACC8(wv) }
        }
        for (int c = beg + 64; c < end; c += 16) {   // rare deg>64
            if (c + q < end)     { uint4 wv = hsb[(size_t)csr[c + q] * 8 + r]; ACC8(wv) }
            if (c + 8 + q < end) { uint4 wv = hsb[(size_t)csr[c + 8 + q] * 8 + r]; ACC8(wv) }
        }
#pragma unroll
        for (int i = 0; i < 8; i++) {
            acc[i] += __shfl_xor(acc[i], 8, 64);
            acc[i] += __shfl_xor(acc[i], 16, 64);
            acc[i] += __shfl_xor(acc[i], 32, 64);
        }
        ACC8(wsf)
        float v[8];
#pragma unroll
        for (int i = 0; i < 8; i++) v[i] = fmaxf(acc[i] * di + b1r[i], 0.f);
        float h[4] = {0.f, 0.f, 0.f, 0.f};
#pragma unroll
        for (int i = 0; i < 8; i++)
#pragma unroll
            for (int jj = 0; jj < 4; jj++) h[jj] += v[i] * w2r[i][jj];
#pragma unroll
        for (int jj = 0; jj < 4; jj++) {
            h[jj] += __shfl_xor(h[jj], 1, 64);
            h[jj] += __shfl_xor(h[jj], 2, 64);
            h[jj] += __shfl_xor(h[jj], 4, 64);
        }
        if (r == 0) {
            unsigned p0 = pack_bf16(h[0] * di, h[1] * di);
            unsigned p1 = pack_bf16(h[2] * di, h[3] * di);
            *(uint2*)(hsb2 + (size_t)d * 16 + 2 * q) = make_uint2(p0, p1);
        }
        beg = nbeg; end = nend; cc = ncc; idxv = nidxv;
    }
}

// Fused layer-2 aggregate + relu + 32x10 classifier + log_softmax -> out.
// Lane (q=lane>>2 in 0..15, r=lane&3). Gather: 4 lanes/row, 16 edge slots.
__global__ __launch_bounds__(256) void k_agg32f(
        const int* __restrict__ rowptr, const int* __restrict__ csr,
        const uint4* __restrict__ hsb2, const float* __restrict__ dinv,
        const float* __restrict__ b2, const float* __restrict__ Wc,
        const float* __restrict__ bc, float* __restrict__ out, int n) {
    int wid = (blockIdx.x * blockDim.x + threadIdx.x) >> 6;
    int lane = threadIdx.x & 63;
    int q = lane >> 2, r = lane & 3;
    int d0 = wid * NPW;
    if (d0 >= n) return;
    float wcr[8];
    float b2r[8];
    float bcr = (q < 10) ? bc[q] : 0.f;
#pragma unroll
    for (int i = 0; i < 8; i++) {
        b2r[i] = b2[8 * r + i];
        wcr[i] = (q < 10) ? Wc[(8 * r + i) * 10 + q] : 0.f;
    }
    int dend = min(d0 + NPW, n);
    int rp = rowptr[min(d0 + min(lane, NPW), n)];
    int beg = __shfl(rp, 0, 64);
    int end = __shfl(rp, 1, 64);
    int cc = min(end - beg, 64);
    int idxv = (lane < cc) ? csr[beg + lane] : 0;
    for (int d = d0; d < dend; d++) {
        int kk = d - d0;
        int nbeg = __shfl(rp, min(kk + 1, NPW), 64);
        int nend = __shfl(rp, min(kk + 2, NPW), 64);
        int ncc = min(nend - nbeg, 64);
        int nidxv = 0;
        if (d + 1 < dend) nidxv = (lane < ncc) ? csr[nbeg + lane] : 0;
        uint4 wsf = hsb2[(size_t)d * 4 + r];   // self row: issue early
        float di = dinv[d];
        float acc[8];
#pragma unroll
        for (int i = 0; i < 8; i++) acc[i] = 0.f;
        int j = 0;
        for (; j + 32 <= cc; j += 32) {
            int sA = __shfl(idxv, j + q, 64);
            int sB = __shfl(idxv, j + 16 + q, 64);
            uint4 wA = hsb2[(size_t)sA * 4 + r];
            uint4 wB = hsb2[(size_t)sB * 4 + r];
            ACC8(wA)
            ACC8(wB)
        }
        {   // tail: shfl hoisted above the divergent guard (all lanes active)
            int tA = j + q, tB = j + 16 + q;
            int sA = __shfl(idxv, tA & 63, 64);
            int sB = __shfl(idxv, tB & 63, 64);
            if (tA < cc) { uint4 wv = hsb2[(size_t)sA * 4 + r]; ACC8(wv) }
            if (tB < cc) { uint4 wv = hsb2[(size_t)sB * 4 + r]; ACC8(wv) }
        }
        for (int c = beg + 64; c < end; c += 32) {   // rare deg>64
            if (c + q < end)      { uint4 wv = hsb2[(size_t)csr[c + q] * 4 + r]; ACC8(wv) }
            if (c + 16 + q < end) { uint4 wv = hsb2[(size_t)csr[c + 16 + q] * 4 + r]; ACC8(wv) }
        }
#pragma unroll
        for (int i = 0; i < 8; i++) {
            acc[i] += __shfl_xor(acc[i], 4, 64);
            acc[i] += __shfl_xor(acc[i], 8, 64);
            acc[i] += __shfl_xor(acc[i], 16, 64);
            acc[i] += __shfl_xor(acc[i], 32, 64);
        }
        ACC8(wsf)
        float part = 0.f;
#pragma unroll
        for (int i = 0; i < 8; i++) {
            float v = fmaxf(acc[i] * di + b2r[i], 0.f);
            part += v * wcr[i];
        }
        part += __shfl_xor(part, 1, 64);
        part += __shfl_xor(part, 2, 64);
        float mylogit = part + bcr;
        float m = -1e30f;
        float l[10];
#pragma unroll
        for (int c = 0; c < 10; c++) {
            l[c] = __shfl(mylogit, 4 * c, 64);
            m = fmaxf(m, l[c]);
        }
        float ssum = 0.f;
#pragma unroll
        for (int c = 0; c < 10; c++) ssum += __expf(l[c] - m);
        float lse = m + __logf(ssum);
        if (r == 0 && q < 10) out[(size_t)d * 10 + q] = mylogit - lse;
        beg = nbeg; end = nend; cc = ncc; idxv = nidxv;
    }
}

extern "C" void kernel_launch(void* const* d_in, const int* in_sizes, int n_in,
                              void* d_out, int out_size, void* d_ws, size_t ws_size,
                              hipStream_t stream) {
    const float* x  = (const float*)d_in[0];
    const int*   ei = (const int*)d_in[1];
    const float* W1 = (const float*)d_in[2];
    const float* b1 = (const float*)d_in[3];
    const float* W2 = (const float*)d_in[4];
    const float* b2 = (const float*)d_in[5];
    const float* Wc = (const float*)d_in[6];
    const float* bc = (const float*)d_in[7];
    float* out = (float*)d_out;

    const int N = in_sizes[0] / 128;
    const int E = in_sizes[1] / 2;
    const int* src = ei;
    const int* dst = ei + E;

    const int NBUCK = (N + BMASK) >> BSHIFT;   // <= 512
    const int NTILE = (E + TILE - 1) / TILE;
    const int NW = (N + NPW - 1) / NPW;        // waves for fused agg kernels

    char* ws = (char*)d_ws;
    size_t off = 0;
    auto alloc = [&](size_t elems) {
        void* p = ws + off;
        off += ((elems * 4 + 1023) & ~(size_t)1023);
        return p;
    };
    float*    dinv   = (float*)alloc(N);
    int*      bcnt   = (int*)alloc(NBUCK_MAX);   // adjacent to gcur0: one memset
    int*      gcur0  = (int*)alloc(NBUCK_MAX);
    int*      rowptr = (int*)alloc(N + 1);
    int*      binned = (int*)alloc(E);
    int*      csr    = (int*)alloc(E);
    unsigned* hsb    = (unsigned*)alloc((size_t)N * 32);  // layer1 bf16 rows (128 B)
    unsigned* hsb2   = (unsigned*)alloc((size_t)N * 16);  // layer2 bf16 rows (64 B)

    hipMemsetAsync(bcnt, 0, sizeof(int) * NBUCK_MAX * 2, stream);  // bcnt + gcur0

    // CSR build
    k_hist<<<512, 256, 0, stream>>>(dst, bcnt, E);
    k_binA<<<NTILE, 256, 0, stream>>>(src, dst, bcnt, gcur0, binned, E);
    k_sortcsr<<<NBUCK, 256, 0, stream>>>(bcnt, binned, rowptr, dinv, csr, N, E);

    // Layer 1: 128 -> 64 (R=2: 128 rows/block)
    k_gemm<128, 64, 2><<<(N + 127) / 128, 256, 0, stream>>>(x, W1, dinv, hsb, N);
    // Fused agg1 + relu + gemm2 -> hsb2
    k_agg64f<<<(NW * 64 + 255) / 256, 256, 0, stream>>>(rowptr, csr, (const uint4*)hsb,
                                                        dinv, b1, W2, hsb2, N);
    // Fused agg2 + relu + classifier + log_softmax -> out
    k_agg32f<<<(NW * 64 + 255) / 256, 256, 0, stream>>>(rowptr, csr, (const uint4*)hsb2,
                                                        dinv, b2, Wc, bc, out, N);
}